// Round 22
// baseline (45.021 us; speedup 1.0000x reference)
//
#include <hip/hip_runtime.h>
#include <hip/hip_bf16.h>
#include <math.h>

// ---------------- problem constants ----------------
#define N_ROWS 8192
#define DIM 64
#define TEMP 0.07f
#define MARGIN 1.0f
#define CLIPV 1.0000001f     // fp32 nearest of 1+1e-7 (validated vs ref: R1 absmax 1.9e-9)
#define NUM_HARD 5
#define CAP 8192             // correction-record capacity (measured: 0 records on this data)

// R22: R16 structure (26.0us best) minus one dispatch — finalize runs as a
// __noinline__ epilogue call from pair's last-done block (call ABI isolates the
// epilogue's register pressure from the hot loop; R13's inline tail forced VGPR 32).
#define BM 128
#define BN 128
#define GRID_DIM (N_ROWS / BN)                      // 64
#define NBLK_WORK (GRID_DIM * (GRID_DIM + 1) / 2)   // 2080 working blocks

typedef short bf16x8 __attribute__((ext_vector_type(8)));
typedef float f32x4 __attribute__((ext_vector_type(4)));

__device__ inline short f2bf(float f) {           // RNE float->bf16 (bit-level, ABI-free)
    unsigned u = __float_as_uint(f);
    unsigned r = (u + 0x7FFFu + ((u >> 16) & 1u)) >> 16;
    return (short)r;
}

__device__ inline void gld_lds16(const void* g, void* l) {
    // async global->LDS, 16B/lane; LDS dest = wave-uniform base + lane*16
    __builtin_amdgcn_global_load_lds((const __attribute__((address_space(1))) unsigned*)g,
                                     (__attribute__((address_space(3))) unsigned*)l, 16, 0, 0);
}

// ---- prep: one row per WAVE; single plain-scaled embS (1 MiB); zero gcnt+done ----
__global__ __launch_bounds__(256) void prep(const float* __restrict__ emb,
                                            short* __restrict__ embS,
                                            int* __restrict__ ctrs) {
    const int row = blockIdx.x * 4 + (threadIdx.x >> 6);
    const int lane = threadIdx.x & 63;
    if (blockIdx.x == 0 && threadIdx.x < 2) ctrs[threadIdx.x] = 0;  // gcnt, done

    float x = emb[(size_t)row * DIM + lane];       // coalesced 256B/wave
    float v = x * x;
    float c = (lane == 63) ? -v : v;               // Minkowski signature
#pragma unroll
    for (int off = 32; off >= 1; off >>= 1)
        c += __shfl_xor(c, off);                   // all lanes get nrm
    float rinv = 1.f / sqrtf(fabsf(c));            // +1e-9 of ref denom < fp32 ulp (R1)
    embS[(size_t)row * DIM + lane] = f2bf(x * rinv);
}

// ---- epilogue: NOINLINE so its serial control flow cannot poison pair's regalloc ----
__device__ __attribute__((noinline)) void epilogue(
    const int* __restrict__ labels, int lstride,
    const int* __restrict__ gcnt,
    int* __restrict__ recI, int* __restrict__ recJ,
    float* __restrict__ recD, float* __restrict__ out)
{
    __shared__ int hist[64];
    int tid = threadIdx.x;
    if (tid < 64) hist[tid] = 0;
    __syncthreads();
    for (int k = tid; k < N_ROWS; k += 256)
        atomicAdd(&hist[labels[(size_t)k * lstride] & 63], 1);
    __syncthreads();

    if (tid != 0) return;
    const float f = acoshf(CLIPV);                 // d everywhere ratio<=clip (validated R1)
    const float hbase = fmaxf(MARGIN - f, 0.f);
    long long pos_cnt = 0;
    for (int c = 0; c < 64; ++c)
        pos_cnt += (long long)hist[c] * (long long)(hist[c] - 1);
    long long neg_cnt = (long long)N_ROWS * (N_ROWS - 1) - pos_cnt;
    if (pos_cnt < 1) pos_cnt = 1;
    if (neg_cnt < 1) neg_cnt = 1;

    int C = *gcnt; if (C > CAP) C = CAP; if (C < 0) C = 0;
    // deterministic order: insertion sort by (i, d, j) — unique (i,j) keys
    for (int p = 1; p < C; ++p) {
        int ii = recI[p], jj = recJ[p]; float dd = recD[p];
        int q = p - 1;
        while (q >= 0 && (recI[q] > ii ||
               (recI[q] == ii && (recD[q] > dd ||
               (recD[q] == dd && recJ[q] > jj))))) {
            recI[q+1] = recI[q]; recJ[q+1] = recJ[q]; recD[q+1] = recD[q];
            --q;
        }
        recI[q+1] = ii; recJ[q+1] = jj; recD[q+1] = dd;
    }
    float pos_corr = 0.f, neg_corr = 0.f, hdelta = 0.f;
    int p = 0;
    while (p < C) {
        int i = recI[p];
        int q = p;
        while (q < C && recI[q] == i) ++q;
        int li = labels[(size_t)i * lstride];
        int negrec = 0;
        for (int r = p; r < q; ++r) {
            bool same = (labels[(size_t)recJ[r] * lstride] == li);
            float e = recD[r] - f;
            if (same) pos_corr += e; else { neg_corr += e; ++negrec; }
        }
        int neg_i = N_ROWS - hist[li & 63];
        int floor_i = neg_i - negrec;              // negatives still at d_floor
        if (floor_i < NUM_HARD) {                  // top-5 no longer all d_floor
            int kf = floor_i < 0 ? 0 : (floor_i > NUM_HARD ? NUM_HARD : floor_i);
            int need = NUM_HARD - kf;
            float ns = kf * hbase;
            int got = 0;
            for (int r = p; r < q && got < need; ++r) {       // d-ascending within row
                if (labels[(size_t)recJ[r] * lstride] != li) {
                    ns += fmaxf(MARGIN - recD[r], 0.f); ++got;
                }
            }
            hdelta += ns / (float)NUM_HARD - hbase;
        }
        p = q;
    }
    float possum = f * (float)pos_cnt + pos_corr;
    float negsum = f * (float)neg_cnt + neg_corr;
    float pos_loss = (possum / TEMP) / (float)pos_cnt;
    float neg_loss = -(negsum / TEMP) / (float)neg_cnt;
    float contrastive = pos_loss + neg_loss;
    float hn = ((float)N_ROWS * hbase + hdelta) / (float)N_ROWS;
    out[0] = contrastive + hn;
    out[1] = contrastive;
    out[2] = hn;
}

// ---- pair: R16 body verbatim + last-block-done tail calling noinline epilogue ----
__global__ __launch_bounds__(256, 4) void pair_mfma(
    const short* __restrict__ embS, const int* __restrict__ labels, int lstride,
    int* __restrict__ ctrs, int* __restrict__ recI, int* __restrict__ recJ,
    float* __restrict__ recD, float* __restrict__ out)
{
    const int bx = blockIdx.x, by = blockIdx.y;
    if (by > bx) return;                           // triangular: 2080 of 4096 blocks work
    const bool mirror = (bx != by);

    __shared__ short lB[BN * DIM];                 // 16 KiB
    __shared__ int s_last;

    const int tid = threadIdx.x;
    const int lane = tid & 63;
    const int w = tid >> 6;
    const int arow0 = by * BM;
    const int bcol0 = bx * BN;
    int* gcnt = ctrs;
    int* done = ctrs + 1;

    // stage B (16 KiB = 4 issues/wave). Linear LDS dest; source pre-swizzled:
    // LDS slot s of row R holds k-group g = s ^ (R&7)  (read applies same XOR)
#pragma unroll
    for (int q = 0; q < 4; ++q) {
        int issue = w * 4 + q;                     // wave-uniform
        int byte = issue * 1024 + lane * 16;
        int R = byte >> 7;                         // local row (128B/row)
        int s = (byte >> 4) & 7;
        int g = s ^ (R & 7);
        gld_lds16(embS + (size_t)(bcol0 + R) * DIM + g * 8, lB + issue * 512);
    }

    const int r15 = lane & 15, l4 = lane >> 4;

    // A fragments: 2 strips x 2 K-halves, straight from global (coalesced 64B/row)
    bf16x8 a[2][2];
#pragma unroll
    for (int s = 0; s < 2; ++s) {
        int row = arow0 + w * 32 + s * 16 + r15;
#pragma unroll
        for (int h = 0; h < 2; ++h)
            a[s][h] = *reinterpret_cast<const bf16x8*>(
                embS + (size_t)row * DIM + (h * 4 + l4) * 8);
    }
    __syncthreads();                               // drains vmcnt (B in LDS ready)

    // Minkowski: negate x63 of each staged B row in LDS (elem 63 lives in
    // k-group 7 -> swizzled slot 7^(R&7), short 7). bf16 negate = XOR 0x8000.
    if (tid < BN)
        lB[tid * DIM + ((7 ^ (tid & 7)) * 8) + 7] ^= (short)0x8000;
    __syncthreads();

    bool wrote = false;
#pragma unroll
    for (int t = 0; t < 8; ++t) {                  // all 8 col-sets of 16
        int L = t * 16 + r15;
        int slot0 = l4 ^ (L & 7);
        int slot1 = (4 + l4) ^ (L & 7);
        bf16x8 b0 = *reinterpret_cast<const bf16x8*>(&lB[L * DIM + slot0 * 8]);
        bf16x8 b1 = *reinterpret_cast<const bf16x8*>(&lB[L * DIM + slot1 * 8]);
        f32x4 c[2];
#pragma unroll
        for (int s = 0; s < 2; ++s) {
            f32x4 z = { 0.f, 0.f, 0.f, 0.f };
            z = __builtin_amdgcn_mfma_f32_16x16x32_bf16(a[s][0], b0, z, 0, 0, 0);
            c[s] = __builtin_amdgcn_mfma_f32_16x16x32_bf16(a[s][1], b1, z, 0, 0, 0);
        }
        int j = bcol0 + t * 16 + r15;
#pragma unroll
        for (int s = 0; s < 2; ++s) {
            float m = fmaxf(fmaxf(fabsf(c[s][0]), fabsf(c[s][1])),
                            fmaxf(fabsf(c[s][2]), fabsf(c[s][3])));
            if (m > CLIPV) {                       // ~never (execz skip)
#pragma unroll 1
                for (int r = 0; r < 4; ++r) {
                    float av = fabsf(c[s][r]);
                    if (av > CLIPV) {
                        int i = arow0 + w * 32 + s * 16 + l4 * 4 + r;  // C/D row map
                        if (i != j) {
                            float d = acoshf(av);
                            int idx = atomicAdd(gcnt, 1);
                            if (idx < CAP) { recI[idx] = i; recJ[idx] = j; recD[idx] = d; }
                            if (mirror) {          // (j,i) tile is skipped -> emit here
                                int idx2 = atomicAdd(gcnt, 1);
                                if (idx2 < CAP) { recI[idx2] = j; recJ[idx2] = i; recD[idx2] = d; }
                            }
                            wrote = true;
                        }
                    }
                }
            }
        }
    }

    // ---------------- last-block-done tail ----------------
    if (wrote) __threadfence();                    // release records (rare path only)
    __syncthreads();
    if (tid == 0) {
        int old = atomicAdd(done, 1);
        s_last = (old == NBLK_WORK - 1) ? 1 : 0;
    }
    __syncthreads();
    if (!s_last) return;
    if (tid == 0) __threadfence();                 // acquire records (1 block)
    __syncthreads();
    epilogue(labels, lstride, gcnt, recI, recJ, recD, out);  // noinline call
}

extern "C" void kernel_launch(void* const* d_in, const int* in_sizes, int n_in,
                              void* d_out, int out_size, void* d_ws, size_t ws_size,
                              hipStream_t stream) {
    const float* emb = (const float*)d_in[0];
    const int* labels = (const int*)d_in[1];
    int lstride = (n_in > 1 && in_sizes[1] >= 2 * N_ROWS) ? 2 : 1;
    float* out = (float*)d_out;

    char* wsb = (char*)d_ws;
    int* ctrs = (int*)wsb;                                   // [0]=gcnt [1]=done
    short* embS = (short*)(wsb + 1024);                      // 1 MiB
    int* recI = (int*)(wsb + 1024 + (size_t)N_ROWS * DIM * 2);
    int* recJ = recI + CAP;
    float* recD = (float*)(recJ + CAP);

    hipLaunchKernelGGL(prep, dim3(N_ROWS / 4), dim3(256), 0, stream,
                       emb, embS, ctrs);
    hipLaunchKernelGGL(pair_mfma, dim3(GRID_DIM, GRID_DIM), dim3(256), 0, stream,
                       embS, labels, lstride, ctrs, recI, recJ, recD, out);
}

// Round 23
// 23.730 us; speedup vs baseline: 1.8972x; 1.8972x over previous
//
#include <hip/hip_runtime.h>
#include <hip/hip_bf16.h>
#include <math.h>

// ---------------- problem constants ----------------
#define N_ROWS 8192
#define DIM 64
#define TEMP 0.07f
#define MARGIN 1.0f
#define CLIPV 1.0000001f     // fp32 nearest of 1+1e-7 (validated vs ref: R1 absmax 1.9e-9)
#define NUM_HARD 5
#define CAP 8192             // correction-record capacity (measured: 0 records on this data)

// R23 = R16 base (26.0us best) + hist partials in prep (32 blocks, LDS atomics +
// plain stores — R2/R4-proven) so finalize reads 8KB warm partials, not 64KB cold labels.
#define BM 128
#define BN 128
#define GRID_DIM (N_ROWS / BN)                      // 64
#define NHISTBLK 32

typedef short bf16x8 __attribute__((ext_vector_type(8)));
typedef float f32x4 __attribute__((ext_vector_type(4)));

__device__ inline short f2bf(float f) {           // RNE float->bf16 (bit-level, ABI-free)
    unsigned u = __float_as_uint(f);
    unsigned r = (u + 0x7FFFu + ((u >> 16) & 1u)) >> 16;
    return (short)r;
}

__device__ inline void gld_lds16(const void* g, void* l) {
    // async global->LDS, 16B/lane; LDS dest = wave-uniform base + lane*16
    __builtin_amdgcn_global_load_lds((const __attribute__((address_space(1))) unsigned*)g,
                                     (__attribute__((address_space(3))) unsigned*)l, 16, 0, 0);
}

// ---- prep: one row per WAVE; embS (1 MiB); first 32 blocks also hist 256 labels each ----
__global__ __launch_bounds__(256) void prep(const float* __restrict__ emb,
                                            const int* __restrict__ labels, int lstride,
                                            short* __restrict__ embS,
                                            int* __restrict__ ctrs,
                                            int* __restrict__ hist_part) {
    __shared__ int h[64];
    const int tid = threadIdx.x;
    const int blk = blockIdx.x;
    const int row = blk * 4 + (tid >> 6);
    const int lane = tid & 63;
    const bool histb = (blk < NHISTBLK);
    if (blk == 0 && tid == 0) ctrs[0] = 0;         // gcnt (stream order)
    if (histb) {
        if (tid < 64) h[tid] = 0;
        __syncthreads();
        atomicAdd(&h[labels[(size_t)(blk * 256 + tid) * lstride] & 63], 1);
    }

    float x = emb[(size_t)row * DIM + lane];       // coalesced 256B/wave
    float v = x * x;
    float c = (lane == 63) ? -v : v;               // Minkowski signature
#pragma unroll
    for (int off = 32; off >= 1; off >>= 1)
        c += __shfl_xor(c, off);                   // all lanes get nrm
    float rinv = 1.f / sqrtf(fabsf(c));            // +1e-9 of ref denom < fp32 ulp (R1)
    embS[(size_t)row * DIM + lane] = f2bf(x * rinv);

    if (histb) {
        __syncthreads();
        if (tid < 64) hist_part[blk * 64 + tid] = h[tid];   // plain stores
    }
}

// ---- pair: R16 body verbatim (best measured) ----
__global__ __launch_bounds__(256, 8) void pair_mfma(
    const short* __restrict__ embS,
    int* __restrict__ gcnt, int* __restrict__ recI, int* __restrict__ recJ,
    float* __restrict__ recD)
{
    const int bx = blockIdx.x, by = blockIdx.y;
    if (by > bx) return;                           // triangular: 2080 of 4096 blocks work
    const bool mirror = (bx != by);

    __shared__ short lB[BN * DIM];                 // 16 KiB

    const int tid = threadIdx.x;
    const int lane = tid & 63;
    const int w = tid >> 6;
    const int arow0 = by * BM;
    const int bcol0 = bx * BN;

    // stage B (16 KiB = 4 issues/wave). Linear LDS dest; source pre-swizzled:
    // LDS slot s of row R holds k-group g = s ^ (R&7)  (read applies same XOR)
#pragma unroll
    for (int q = 0; q < 4; ++q) {
        int issue = w * 4 + q;                     // wave-uniform
        int byte = issue * 1024 + lane * 16;
        int R = byte >> 7;                         // local row (128B/row)
        int s = (byte >> 4) & 7;
        int g = s ^ (R & 7);
        gld_lds16(embS + (size_t)(bcol0 + R) * DIM + g * 8, lB + issue * 512);
    }

    const int r15 = lane & 15, l4 = lane >> 4;

    // A fragments: 2 strips x 2 K-halves, straight from global (coalesced 64B/row)
    bf16x8 a[2][2];
#pragma unroll
    for (int s = 0; s < 2; ++s) {
        int row = arow0 + w * 32 + s * 16 + r15;
#pragma unroll
        for (int h = 0; h < 2; ++h)
            a[s][h] = *reinterpret_cast<const bf16x8*>(
                embS + (size_t)row * DIM + (h * 4 + l4) * 8);
    }
    __syncthreads();                               // drains vmcnt (B in LDS ready)

    // Minkowski: negate x63 of each staged B row in LDS (elem 63 lives in
    // k-group 7 -> swizzled slot 7^(R&7), short 7). bf16 negate = XOR 0x8000.
    if (tid < BN)
        lB[tid * DIM + ((7 ^ (tid & 7)) * 8) + 7] ^= (short)0x8000;
    __syncthreads();

#pragma unroll
    for (int t = 0; t < 8; ++t) {                  // all 8 col-sets of 16
        int L = t * 16 + r15;
        int slot0 = l4 ^ (L & 7);
        int slot1 = (4 + l4) ^ (L & 7);
        bf16x8 b0 = *reinterpret_cast<const bf16x8*>(&lB[L * DIM + slot0 * 8]);
        bf16x8 b1 = *reinterpret_cast<const bf16x8*>(&lB[L * DIM + slot1 * 8]);
        f32x4 c[2];
#pragma unroll
        for (int s = 0; s < 2; ++s) {
            f32x4 z = { 0.f, 0.f, 0.f, 0.f };
            z = __builtin_amdgcn_mfma_f32_16x16x32_bf16(a[s][0], b0, z, 0, 0, 0);
            c[s] = __builtin_amdgcn_mfma_f32_16x16x32_bf16(a[s][1], b1, z, 0, 0, 0);
        }
        int j = bcol0 + t * 16 + r15;
#pragma unroll
        for (int s = 0; s < 2; ++s) {
            float m = fmaxf(fmaxf(fabsf(c[s][0]), fabsf(c[s][1])),
                            fmaxf(fabsf(c[s][2]), fabsf(c[s][3])));
            if (m > CLIPV) {                       // ~never (execz skip)
#pragma unroll 1
                for (int r = 0; r < 4; ++r) {
                    float av = fabsf(c[s][r]);
                    if (av > CLIPV) {
                        int i = arow0 + w * 32 + s * 16 + l4 * 4 + r;  // C/D row map
                        if (i != j) {
                            float d = acoshf(av);
                            int idx = atomicAdd(gcnt, 1);
                            if (idx < CAP) { recI[idx] = i; recJ[idx] = j; recD[idx] = d; }
                            if (mirror) {          // (j,i) tile is skipped -> emit here
                                int idx2 = atomicAdd(gcnt, 1);
                                if (idx2 < CAP) { recI[idx2] = j; recJ[idx2] = i; recD[idx2] = d; }
                            }
                        }
                    }
                }
            }
        }
    }
}

// ---- finalize: sum 8KB warm partials; labels touched only in C>0 record path ----
__global__ void finalize2(const int* __restrict__ labels, int lstride,
                          const int* __restrict__ gcnt, const int* __restrict__ hist_part,
                          int* __restrict__ recI, int* __restrict__ recJ,
                          float* __restrict__ recD, float* __restrict__ out)
{
    __shared__ int hist[64];
    int tid = threadIdx.x;
    if (tid < 64) {
        int sum = 0;
#pragma unroll 4
        for (int b = 0; b < NHISTBLK; ++b) sum += hist_part[b * 64 + tid];
        hist[tid] = sum;
    }
    __syncthreads();

    if (tid == 0) {
        const float f = acoshf(CLIPV);             // d everywhere ratio<=clip (validated R1)
        const float hbase = fmaxf(MARGIN - f, 0.f);
        long long pos_cnt = 0;
        for (int c = 0; c < 64; ++c)
            pos_cnt += (long long)hist[c] * (long long)(hist[c] - 1);
        long long neg_cnt = (long long)N_ROWS * (N_ROWS - 1) - pos_cnt;
        if (pos_cnt < 1) pos_cnt = 1;
        if (neg_cnt < 1) neg_cnt = 1;

        int C = *gcnt; if (C > CAP) C = CAP; if (C < 0) C = 0;
        // deterministic order: insertion sort by (i, d, j) — unique (i,j) keys
        for (int p = 1; p < C; ++p) {
            int ii = recI[p], jj = recJ[p]; float dd = recD[p];
            int q = p - 1;
            while (q >= 0 && (recI[q] > ii ||
                   (recI[q] == ii && (recD[q] > dd ||
                   (recD[q] == dd && recJ[q] > jj))))) {
                recI[q+1] = recI[q]; recJ[q+1] = recJ[q]; recD[q+1] = recD[q];
                --q;
            }
            recI[q+1] = ii; recJ[q+1] = jj; recD[q+1] = dd;
        }
        float pos_corr = 0.f, neg_corr = 0.f, hdelta = 0.f;
        int p = 0;
        while (p < C) {                            // skipped entirely when C==0
            int i = recI[p];
            int q = p;
            while (q < C && recI[q] == i) ++q;
            int li = labels[(size_t)i * lstride];
            int negrec = 0;
            for (int r = p; r < q; ++r) {
                bool same = (labels[(size_t)recJ[r] * lstride] == li);
                float e = recD[r] - f;
                if (same) pos_corr += e; else { neg_corr += e; ++negrec; }
            }
            int neg_i = N_ROWS - hist[li & 63];
            int floor_i = neg_i - negrec;          // negatives still at d_floor
            if (floor_i < NUM_HARD) {              // top-5 no longer all d_floor
                int kf = floor_i < 0 ? 0 : (floor_i > NUM_HARD ? NUM_HARD : floor_i);
                int need = NUM_HARD - kf;
                float ns = kf * hbase;
                int got = 0;
                for (int r = p; r < q && got < need; ++r) {   // d-ascending within row
                    if (labels[(size_t)recJ[r] * lstride] != li) {
                        ns += fmaxf(MARGIN - recD[r], 0.f); ++got;
                    }
                }
                hdelta += ns / (float)NUM_HARD - hbase;
            }
            p = q;
        }
        float possum = f * (float)pos_cnt + pos_corr;
        float negsum = f * (float)neg_cnt + neg_corr;
        float pos_loss = (possum / TEMP) / (float)pos_cnt;
        float neg_loss = -(negsum / TEMP) / (float)neg_cnt;
        float contrastive = pos_loss + neg_loss;
        float hn = ((float)N_ROWS * hbase + hdelta) / (float)N_ROWS;
        out[0] = contrastive + hn;
        out[1] = contrastive;
        out[2] = hn;
    }
}

extern "C" void kernel_launch(void* const* d_in, const int* in_sizes, int n_in,
                              void* d_out, int out_size, void* d_ws, size_t ws_size,
                              hipStream_t stream) {
    const float* emb = (const float*)d_in[0];
    const int* labels = (const int*)d_in[1];
    int lstride = (n_in > 1 && in_sizes[1] >= 2 * N_ROWS) ? 2 : 1;
    float* out = (float*)d_out;

    char* wsb = (char*)d_ws;
    int* ctrs = (int*)wsb;                                   // [0]=gcnt
    int* hist_part = (int*)(wsb + 256);                      // 32*64 ints = 8 KiB
    short* embS = (short*)(wsb + 16384);                     // 1 MiB
    int* recI = (int*)(wsb + 16384 + (size_t)N_ROWS * DIM * 2);
    int* recJ = recI + CAP;
    float* recD = (float*)(recJ + CAP);

    hipLaunchKernelGGL(prep, dim3(N_ROWS / 4), dim3(256), 0, stream,
                       emb, labels, lstride, embS, ctrs, hist_part);
    hipLaunchKernelGGL(pair_mfma, dim3(GRID_DIM, GRID_DIM), dim3(256), 0, stream,
                       embS, ctrs, recI, recJ, recD);
    hipLaunchKernelGGL(finalize2, dim3(1), dim3(256), 0, stream,
                       labels, lstride, ctrs, hist_part, recI, recJ, recD, out);
}